// Round 1
// baseline (7972.404 us; speedup 1.0000x reference)
//
#include <hip/hip_runtime.h>
#include <hip/hip_bf16.h>

#define F_IN 512
#define H_DIM 256
#define C_DIM 64
#define K_STEPS 10
#define ALPHA 0.1f

// ---------------------------------------------------------------------------
// Fused MLP: h = relu(x @ W1 + b1) @ W2 + b2
// One block = 16 rows. x tile staged in LDS (32KB), h1 tile in LDS (16KB).
// Phase 1: thread t computes h1 column t for all 16 rows (broadcast LDS reads,
// unrolled k by 4 -> ds_read_b128, 4 LDS instrs / 16 FMA).
// Phase 2: wave w computes rows 4w..4w+3, lane j = column j of C.
// ---------------------------------------------------------------------------
__global__ __launch_bounds__(256) void mlp_kernel(
    const float* __restrict__ x,
    const float* __restrict__ W1, const float* __restrict__ b1,
    const float* __restrict__ W2, const float* __restrict__ b2,
    float* __restrict__ h)
{
    __shared__ float xs[16 * F_IN];    // 32 KB
    __shared__ float h1s[16 * H_DIM];  // 16 KB

    const int t = threadIdx.x;
    const long row0 = (long)blockIdx.x * 16;

    // load x tile: 16*512 floats = 2048 float4, 8 per thread, coalesced
    {
        const float4* xg = (const float4*)(x + row0 * F_IN);
        float4* xs4 = (float4*)xs;
        #pragma unroll
        for (int i = 0; i < 8; ++i) xs4[i * 256 + t] = xg[i * 256 + t];
    }
    __syncthreads();

    // phase 1: h1[r][t] for r in 0..15
    float acc[16];
    #pragma unroll
    for (int r = 0; r < 16; ++r) acc[r] = 0.f;

    for (int k = 0; k < F_IN; k += 4) {
        const float w0 = W1[(k + 0) * H_DIM + t];
        const float w1 = W1[(k + 1) * H_DIM + t];
        const float w2 = W1[(k + 2) * H_DIM + t];
        const float w3 = W1[(k + 3) * H_DIM + t];
        #pragma unroll
        for (int r = 0; r < 16; ++r) {
            const float4 xv = *(const float4*)&xs[r * F_IN + k];
            acc[r] += xv.x * w0;
            acc[r] += xv.y * w1;
            acc[r] += xv.z * w2;
            acc[r] += xv.w * w3;
        }
    }
    {
        const float bb = b1[t];
        #pragma unroll
        for (int r = 0; r < 16; ++r) {
            const float v = acc[r] + bb;
            h1s[r * H_DIM + t] = v > 0.f ? v : 0.f;
        }
    }
    __syncthreads();

    // phase 2: h[r][j] = sum_k h1[r][k] * W2[k][j] + b2[j]
    const int j = t & 63;
    const int r0 = (t >> 6) * 4;
    float acc2[4] = {0.f, 0.f, 0.f, 0.f};
    for (int k = 0; k < H_DIM; k += 4) {
        const float w0 = W2[(k + 0) * C_DIM + j];
        const float w1 = W2[(k + 1) * C_DIM + j];
        const float w2 = W2[(k + 2) * C_DIM + j];
        const float w3 = W2[(k + 3) * C_DIM + j];
        #pragma unroll
        for (int r = 0; r < 4; ++r) {
            const float4 hv = *(const float4*)&h1s[(r0 + r) * H_DIM + k];
            acc2[r] += hv.x * w0;
            acc2[r] += hv.y * w1;
            acc2[r] += hv.z * w2;
            acc2[r] += hv.w * w3;
        }
    }
    {
        const float bb = b2[j];
        #pragma unroll
        for (int r = 0; r < 4; ++r)
            h[(row0 + r0 + r) * C_DIM + j] = acc2[r] + bb;
    }
}

// ---------------------------------------------------------------------------
// Degree / norm precompute
// ---------------------------------------------------------------------------
__global__ void initdeg_kernel(float* __restrict__ deg, int n)
{
    int i = blockIdx.x * 256 + threadIdx.x;
    if (i < n) deg[i] = 1.0f;  // self-loop contributes 1
}

__global__ void countdeg_kernel(const int* __restrict__ col, float* __restrict__ deg, int e)
{
    int i = blockIdx.x * 256 + threadIdx.x;
    if (i < e) atomicAdd(&deg[col[i]], 1.0f);
}

__global__ void finishdeg_kernel(float* __restrict__ dinv, float* __restrict__ selfnorm, int n)
{
    int i = blockIdx.x * 256 + threadIdx.x;
    if (i < n) {
        const float d = dinv[i];             // deg (>= 1 always)
        const float di = rsqrtf(d);
        dinv[i] = di;
        selfnorm[i] = di * di;
    }
}

__global__ void norm_kernel(const int* __restrict__ row, const int* __restrict__ col,
                            const float* __restrict__ dinv, float* __restrict__ norm, int e)
{
    int i = blockIdx.x * 256 + threadIdx.x;
    if (i < e) norm[i] = dinv[row[i]] * dinv[col[i]];
}

// ---------------------------------------------------------------------------
// APPNP propagation
// ---------------------------------------------------------------------------
__global__ __launch_bounds__(256) void scatter_kernel(
    const int* __restrict__ row, const int* __restrict__ col,
    const float* __restrict__ norm, const float* __restrict__ z,
    float* __restrict__ agg, long e)
{
    const long gid = (long)blockIdx.x * 256 + threadIdx.x;
    const long ei = gid >> 6;
    const int c = (int)(gid & 63);
    if (ei < e) {
        const int r = row[ei];
        const int cl = col[ei];
        const float v = z[(long)r * C_DIM + c] * norm[ei];
        atomicAdd(&agg[(long)cl * C_DIM + c], v);
    }
}

__global__ __launch_bounds__(256) void update_kernel(
    const float* __restrict__ agg, const float* __restrict__ selfnorm,
    const float* __restrict__ h, float* __restrict__ z, int n64)
{
    int i = blockIdx.x * 256 + threadIdx.x;
    if (i < n64) {
        const int node = i >> 6;
        z[i] = (1.0f - ALPHA) * (agg[i] + z[i] * selfnorm[node]) + ALPHA * h[i];
    }
}

// ---------------------------------------------------------------------------
// Row log-softmax over 64 channels: one wave per row
// ---------------------------------------------------------------------------
__global__ __launch_bounds__(256) void lsm_kernel(
    const float* __restrict__ z, float* __restrict__ out, int nrows)
{
    const int gid = blockIdx.x * 256 + threadIdx.x;
    const int rowi = gid >> 6;
    const int lane = threadIdx.x & 63;
    if (rowi < nrows) {
        const float v = z[(long)rowi * C_DIM + lane];
        float m = v;
        #pragma unroll
        for (int o = 32; o > 0; o >>= 1) m = fmaxf(m, __shfl_xor(m, o, 64));
        const float ex = expf(v - m);
        float s = ex;
        #pragma unroll
        for (int o = 32; o > 0; o >>= 1) s += __shfl_xor(s, o, 64);
        out[(long)rowi * C_DIM + lane] = v - m - logf(s);
    }
}

// ---------------------------------------------------------------------------
extern "C" void kernel_launch(void* const* d_in, const int* in_sizes, int n_in,
                              void* d_out, int out_size, void* d_ws, size_t ws_size,
                              hipStream_t stream)
{
    const float* x  = (const float*)d_in[0];
    const int* ei   = (const int*)d_in[1];
    const float* W1 = (const float*)d_in[2];
    const float* b1 = (const float*)d_in[3];
    const float* W2 = (const float*)d_in[4];
    const float* b2 = (const float*)d_in[5];
    float* out = (float*)d_out;

    const int N = in_sizes[0] / F_IN;       // 100000
    const long E = in_sizes[1] / 2;         // 3200000
    const int* row = ei;                    // edge_index[0] (source)
    const int* col = ei + E;                // edge_index[1] (target)

    // workspace layout (floats)
    float* ws = (float*)d_ws;
    float* h        = ws;                   // N*64
    float* norm     = h + (long)N * C_DIM;  // E
    float* dinv     = norm + E;             // N  (holds deg first)
    float* selfnorm = dinv + N;             // N
    float* z        = selfnorm + N;         // N*64
    float* agg      = z + (long)N * C_DIM;  // N*64

    const int nblk = (N + 255) / 256;
    const int eblk = (int)((E + 255) / 256);

    // 1. MLP encoder
    mlp_kernel<<<N / 16, 256, 0, stream>>>(x, W1, b1, W2, b2, h);

    // 2. degrees + norms
    initdeg_kernel<<<nblk, 256, 0, stream>>>(dinv, N);
    countdeg_kernel<<<eblk, 256, 0, stream>>>(col, dinv, (int)E);
    finishdeg_kernel<<<nblk, 256, 0, stream>>>(dinv, selfnorm, N);
    norm_kernel<<<eblk, 256, 0, stream>>>(row, col, dinv, norm, (int)E);

    // 3. z = h
    hipMemcpyAsync(z, h, (size_t)N * C_DIM * sizeof(float),
                   hipMemcpyDeviceToDevice, stream);

    // 4. APPNP iterations
    const long lanes = E * C_DIM;
    const int sblk = (int)((lanes + 255) / 256);
    const int ublk = (N * C_DIM + 255) / 256;
    for (int it = 0; it < K_STEPS; ++it) {
        hipMemsetAsync(agg, 0, (size_t)N * C_DIM * sizeof(float), stream);
        scatter_kernel<<<sblk, 256, 0, stream>>>(row, col, norm, z, agg, E);
        update_kernel<<<ublk, 256, 0, stream>>>(agg, selfnorm, h, z, N * C_DIM);
    }

    // 5. log-softmax -> out
    lsm_kernel<<<(N * C_DIM + 255) / 256, 256, 0, stream>>>(z, out, N);
}

// Round 2
// 2139.538 us; speedup vs baseline: 3.7262x; 3.7262x over previous
//
#include <hip/hip_runtime.h>
#include <hip/hip_bf16.h>

#define F_IN 512
#define H_DIM 256
#define C_DIM 64
#define K_STEPS 10
#define ALPHA 0.1f

// ---------------------------------------------------------------------------
// Fused MLP: h = relu(x @ W1 + b1) @ W2 + b2   (unchanged from round 1)
// ---------------------------------------------------------------------------
__global__ __launch_bounds__(256) void mlp_kernel(
    const float* __restrict__ x,
    const float* __restrict__ W1, const float* __restrict__ b1,
    const float* __restrict__ W2, const float* __restrict__ b2,
    float* __restrict__ h)
{
    __shared__ float xs[16 * F_IN];    // 32 KB
    __shared__ float h1s[16 * H_DIM];  // 16 KB

    const int t = threadIdx.x;
    const long row0 = (long)blockIdx.x * 16;

    {
        const float4* xg = (const float4*)(x + row0 * F_IN);
        float4* xs4 = (float4*)xs;
        #pragma unroll
        for (int i = 0; i < 8; ++i) xs4[i * 256 + t] = xg[i * 256 + t];
    }
    __syncthreads();

    float acc[16];
    #pragma unroll
    for (int r = 0; r < 16; ++r) acc[r] = 0.f;

    for (int k = 0; k < F_IN; k += 4) {
        const float w0 = W1[(k + 0) * H_DIM + t];
        const float w1 = W1[(k + 1) * H_DIM + t];
        const float w2 = W1[(k + 2) * H_DIM + t];
        const float w3 = W1[(k + 3) * H_DIM + t];
        #pragma unroll
        for (int r = 0; r < 16; ++r) {
            const float4 xv = *(const float4*)&xs[r * F_IN + k];
            acc[r] += xv.x * w0;
            acc[r] += xv.y * w1;
            acc[r] += xv.z * w2;
            acc[r] += xv.w * w3;
        }
    }
    {
        const float bb = b1[t];
        #pragma unroll
        for (int r = 0; r < 16; ++r) {
            const float v = acc[r] + bb;
            h1s[r * H_DIM + t] = v > 0.f ? v : 0.f;
        }
    }
    __syncthreads();

    const int j = t & 63;
    const int r0 = (t >> 6) * 4;
    float acc2[4] = {0.f, 0.f, 0.f, 0.f};
    for (int k = 0; k < H_DIM; k += 4) {
        const float w0 = W2[(k + 0) * C_DIM + j];
        const float w1 = W2[(k + 1) * C_DIM + j];
        const float w2 = W2[(k + 2) * C_DIM + j];
        const float w3 = W2[(k + 3) * C_DIM + j];
        #pragma unroll
        for (int r = 0; r < 4; ++r) {
            const float4 hv = *(const float4*)&h1s[(r0 + r) * H_DIM + k];
            acc2[r] += hv.x * w0;
            acc2[r] += hv.y * w1;
            acc2[r] += hv.z * w2;
            acc2[r] += hv.w * w3;
        }
    }
    {
        const float bb = b2[j];
        #pragma unroll
        for (int r = 0; r < 4; ++r)
            h[(row0 + r0 + r) * C_DIM + j] = acc2[r] + bb;
    }
}

// ---------------------------------------------------------------------------
// CSR build: histogram -> exclusive scan -> fill
// ---------------------------------------------------------------------------
__global__ void hist_kernel(const int* __restrict__ col, int* __restrict__ cnt, int e)
{
    int i = blockIdx.x * 256 + threadIdx.x;
    if (i < e) atomicAdd(&cnt[col[i]], 1);
}

__global__ void dinv_kernel(const int* __restrict__ cnt, float* __restrict__ dinv, int n)
{
    int i = blockIdx.x * 256 + threadIdx.x;
    if (i < n) dinv[i] = rsqrtf((float)cnt[i] + 1.0f);  // +1 self-loop
}

// block scans 1024 elements (256 threads x 4)
__global__ __launch_bounds__(256) void scan1_kernel(
    const int* __restrict__ cnt, int* __restrict__ rowptr, int* __restrict__ sums, int n)
{
    __shared__ int lds[256];
    const int t = threadIdx.x;
    const int base = blockIdx.x * 1024 + t * 4;
    int v[4];
    #pragma unroll
    for (int j = 0; j < 4; ++j) v[j] = (base + j < n) ? cnt[base + j] : 0;
    const int tsum = v[0] + v[1] + v[2] + v[3];
    lds[t] = tsum;
    __syncthreads();
    for (int o = 1; o < 256; o <<= 1) {
        const int add = (t >= o) ? lds[t - o] : 0;
        __syncthreads();
        lds[t] += add;
        __syncthreads();
    }
    int run = lds[t] - tsum;  // exclusive offset within chunk
    #pragma unroll
    for (int j = 0; j < 4; ++j) {
        if (base + j < n) rowptr[base + j] = run;
        run += v[j];
    }
    if (t == 255) sums[blockIdx.x] = lds[255];
}

__global__ __launch_bounds__(128) void scan2_kernel(int* __restrict__ sums, int nc)
{
    __shared__ int lds[128];
    const int t = threadIdx.x;
    const int v = (t < nc) ? sums[t] : 0;
    lds[t] = v;
    __syncthreads();
    for (int o = 1; o < 128; o <<= 1) {
        const int add = (t >= o) ? lds[t - o] : 0;
        __syncthreads();
        lds[t] += add;
        __syncthreads();
    }
    if (t < nc) sums[t] = lds[t] - v;  // exclusive
}

__global__ void scan3_kernel(int* __restrict__ rowptr, const int* __restrict__ sums, int n, int e)
{
    int i = blockIdx.x * 256 + threadIdx.x;
    if (i < n) rowptr[i] += sums[i >> 10];
    else if (i == n) rowptr[n] = e;
}

__global__ void fill_kernel(const int* __restrict__ row, const int* __restrict__ col,
                            const int* __restrict__ rowptr, int* __restrict__ cursor,
                            int* __restrict__ csr_src, int e)
{
    int i = blockIdx.x * 256 + threadIdx.x;
    if (i < e) {
        const int c = col[i];
        const int pos = rowptr[c] + atomicAdd(&cursor[c], 1);
        csr_src[pos] = row[i];
    }
}

// ---------------------------------------------------------------------------
// zs = h * dinv (scaled state; per-edge norm folded into state)
// ---------------------------------------------------------------------------
__global__ void zsinit_kernel(const float* __restrict__ h, const float* __restrict__ dinv,
                              float* __restrict__ zs, int n64)
{
    int i = blockIdx.x * 256 + threadIdx.x;
    if (i < n64) zs[i] = h[i] * dinv[i >> 6];
}

// ---------------------------------------------------------------------------
// Fused APPNP step (gather form): one wave per node, lane = channel.
//   agg = dinv[v] * ( sum_{src in-edges} zs[src] + zs[v] )      (zs = z*dinv)
//   z'  = (1-a)*agg + a*h ;  output zs' = z'*dinv (or z' on final step)
// ---------------------------------------------------------------------------
__global__ __launch_bounds__(256) void gather_kernel(
    const int* __restrict__ rowptr, const int* __restrict__ csr_src,
    const float* __restrict__ dinv, const float* __restrict__ h,
    const float* __restrict__ zs_in, float* __restrict__ outbuf,
    int n, int scaled)
{
    const int node = (blockIdx.x * 256 + threadIdx.x) >> 6;
    const int lane = threadIdx.x & 63;
    if (node >= n) return;

    const int p0 = rowptr[node];
    const int p1 = rowptr[node + 1];
    const long off = (long)node * C_DIM + lane;

    float acc = zs_in[off];  // self-loop term
    int p = p0;
    for (; p + 4 <= p1; p += 4) {
        const int s0 = csr_src[p + 0];
        const int s1 = csr_src[p + 1];
        const int s2 = csr_src[p + 2];
        const int s3 = csr_src[p + 3];
        acc += zs_in[(long)s0 * C_DIM + lane];
        acc += zs_in[(long)s1 * C_DIM + lane];
        acc += zs_in[(long)s2 * C_DIM + lane];
        acc += zs_in[(long)s3 * C_DIM + lane];
    }
    for (; p < p1; ++p) acc += zs_in[(long)csr_src[p] * C_DIM + lane];

    const float di = dinv[node];
    const float znew = (1.0f - ALPHA) * (di * acc) + ALPHA * h[off];
    outbuf[off] = scaled ? znew * di : znew;
}

// ---------------------------------------------------------------------------
// Row log-softmax over 64 channels: one wave per row
// ---------------------------------------------------------------------------
__global__ __launch_bounds__(256) void lsm_kernel(
    const float* __restrict__ z, float* __restrict__ out, int nrows)
{
    const int gid = blockIdx.x * 256 + threadIdx.x;
    const int rowi = gid >> 6;
    const int lane = threadIdx.x & 63;
    if (rowi < nrows) {
        const float v = z[(long)rowi * C_DIM + lane];
        float m = v;
        #pragma unroll
        for (int o = 32; o > 0; o >>= 1) m = fmaxf(m, __shfl_xor(m, o, 64));
        const float ex = expf(v - m);
        float s = ex;
        #pragma unroll
        for (int o = 32; o > 0; o >>= 1) s += __shfl_xor(s, o, 64);
        out[(long)rowi * C_DIM + lane] = v - m - logf(s);
    }
}

// ---------------------------------------------------------------------------
extern "C" void kernel_launch(void* const* d_in, const int* in_sizes, int n_in,
                              void* d_out, int out_size, void* d_ws, size_t ws_size,
                              hipStream_t stream)
{
    const float* x  = (const float*)d_in[0];
    const int* ei   = (const int*)d_in[1];
    const float* W1 = (const float*)d_in[2];
    const float* b1 = (const float*)d_in[3];
    const float* W2 = (const float*)d_in[4];
    const float* b2 = (const float*)d_in[5];
    float* out = (float*)d_out;

    const int N = in_sizes[0] / F_IN;       // 100000
    const int E = in_sizes[1] / 2;          // 3200000
    const int* row = ei;                    // source
    const int* col = ei + E;                // target

    // workspace layout (4-byte units)
    char* ws = (char*)d_ws;
    float* h      = (float*)ws;                              // N*64
    float* zs_a   = h + (long)N * C_DIM;                     // N*64
    float* zs_b   = zs_a + (long)N * C_DIM;                  // N*64
    float* dinv   = zs_b + (long)N * C_DIM;                  // N
    int*   cnt    = (int*)(dinv + N);                        // N
    int*   rowptr = cnt + N;                                 // N+1
    int*   cursor = rowptr + (N + 1);                        // N
    int*   sums   = cursor + N;                              // 128
    int*   csr_src = sums + 128;                             // E

    const int nblk  = (N + 255) / 256;
    const int eblk  = (E + 255) / 256;
    const int nchunks = (N + 1023) / 1024;

    // 1. MLP encoder
    mlp_kernel<<<N / 16, 256, 0, stream>>>(x, W1, b1, W2, b2, h);

    // 2. CSR build + dinv
    hipMemsetAsync(cnt, 0, (size_t)N * sizeof(int), stream);
    hipMemsetAsync(cursor, 0, (size_t)N * sizeof(int), stream);
    hist_kernel<<<eblk, 256, 0, stream>>>(col, cnt, E);
    dinv_kernel<<<nblk, 256, 0, stream>>>(cnt, dinv, N);
    scan1_kernel<<<nchunks, 256, 0, stream>>>(cnt, rowptr, sums, N);
    scan2_kernel<<<1, 128, 0, stream>>>(sums, nchunks);
    scan3_kernel<<<(N + 256) / 256, 256, 0, stream>>>(rowptr, sums, N, E);
    fill_kernel<<<eblk, 256, 0, stream>>>(row, col, rowptr, cursor, csr_src, E);

    // 3. zs_a = h * dinv
    zsinit_kernel<<<(N * C_DIM + 255) / 256, 256, 0, stream>>>(h, dinv, zs_a, N * C_DIM);

    // 4. APPNP iterations (ping-pong; final step writes unscaled z into zs_a)
    const int gblk = (N + 3) / 4;  // 4 waves (nodes) per 256-thread block
    for (int it = 0; it < K_STEPS; ++it) {
        const float* in = (it & 1) ? zs_b : zs_a;
        float* outb     = (it & 1) ? zs_a : zs_b;
        gather_kernel<<<gblk, 256, 0, stream>>>(rowptr, csr_src, dinv, h,
                                                in, outb, N, it < K_STEPS - 1 ? 1 : 0);
    }
    // K_STEPS=10 (even): final output landed in zs_a

    // 5. log-softmax -> out
    lsm_kernel<<<(N * C_DIM + 255) / 256, 256, 0, stream>>>(zs_a, out, N);
}

// Round 3
// 1502.677 us; speedup vs baseline: 5.3055x; 1.4238x over previous
//
#include <hip/hip_runtime.h>
#include <hip/hip_bf16.h>

#define F_IN 512
#define H_DIM 256
#define C_DIM 64
#define K_STEPS 10
#define ALPHA 0.1f

typedef __attribute__((ext_vector_type(8))) short bf16x8;
typedef __attribute__((ext_vector_type(4))) float f32x4;

static __device__ __forceinline__ ushort f2bf(float f) {
    __hip_bfloat16 b = __float2bfloat16(f);
    return *(ushort*)&b;
}
static __device__ __forceinline__ float bf2f(ushort u) {
    union { unsigned int i; float f; } v; v.i = ((unsigned int)u) << 16; return v.f;
}

// ---------------------------------------------------------------------------
// Weight transpose+convert: W1[512][256] -> W1t bf16 [256][512]
// ---------------------------------------------------------------------------
__global__ void prepW1_kernel(const float* __restrict__ W1, ushort* __restrict__ W1t)
{
    const int id = blockIdx.x * 256 + threadIdx.x;     // 131072
    const int k = id & 511, nn = id >> 9;
    W1t[nn * 512 + k] = f2bf(W1[k * 256 + nn]);
}

__global__ void prepW2_kernel(const float* __restrict__ W2, ushort* __restrict__ W2t)
{
    const int id = blockIdx.x * 256 + threadIdx.x;     // 16384
    const int k = id & 255, nn = id >> 8;
    W2t[nn * 256 + k] = f2bf(W2[k * 64 + nn]);
}

// ---------------------------------------------------------------------------
// Fused MFMA MLP: h = relu(x@W1+b1)@W2+b2.  Block = 64 rows, 4 waves.
// Wave w: rows w*16..w*16+15, all 256 cols of h1 (16 frags), then all 64 of h.
// LDS rows padded to 40 (phase1) / 264 (phase2) to kill bank conflicts.
// ---------------------------------------------------------------------------
__global__ __launch_bounds__(256) void mlp_mfma_kernel(
    const float* __restrict__ x,
    const ushort* __restrict__ W1t, const float* __restrict__ b1,
    const ushort* __restrict__ W2t, const float* __restrict__ b2,
    float* __restrict__ h, int n)
{
    __shared__ __align__(16) short w2s[64 * 264];          // 33792 B
    __shared__ __align__(16) char ph1[64 * 264 * 2];       // 33792 B, aliased
    short* xs  = (short*)ph1;                              // [64][40]
    short* w1s = (short*)(ph1 + 64 * 40 * 2);              // [256][40]
    short* h1s = (short*)ph1;                              // [64][264]

    const int t = threadIdx.x;
    const int lane = t & 63;
    const int wv = t >> 6;
    const int ln15 = lane & 15;
    const int hi = lane >> 4;           // 0..3
    const int m0 = wv * 16;
    const long row0 = (long)blockIdx.x * 64;

    // stage W2t -> w2s once (thread t copies 128 B)
    {
        const int r = t >> 2, part = t & 3;
        const uint4* src = (const uint4*)&W2t[r * 256 + part * 64];
        uint4* dst = (uint4*)&w2s[r * 264 + part * 64];
        #pragma unroll
        for (int j = 0; j < 8; ++j) dst[j] = src[j];
    }

    f32x4 acc[16];
    #pragma unroll
    for (int f = 0; f < 16; ++f) acc[f] = (f32x4){0.f, 0.f, 0.f, 0.f};

    const int xr = t >> 3, xq = t & 7;

    for (int ks = 0; ks < 16; ++ks) {
        const int k0 = ks * 32;
        // stage x slice [64][32] fp32 -> bf16
        #pragma unroll
        for (int half = 0; half < 2; ++half) {
            const int rr = xr + half * 32;
            long g = row0 + rr; if (g > (long)n - 1) g = (long)n - 1;
            const float4 v = *(const float4*)&x[g * F_IN + k0 + xq * 4];
            ushort4 p; p.x = f2bf(v.x); p.y = f2bf(v.y); p.z = f2bf(v.z); p.w = f2bf(v.w);
            *(ushort4*)&xs[rr * 40 + xq * 4] = p;
        }
        // stage W1t slice [256][32]: thread t -> row t (64 B)
        {
            const uint4* src = (const uint4*)&W1t[(long)t * F_IN + k0];
            uint4* dst = (uint4*)&w1s[t * 40];
            #pragma unroll
            for (int j = 0; j < 4; ++j) dst[j] = src[j];
        }
        __syncthreads();

        const bf16x8 af = *(const bf16x8*)&xs[(m0 + ln15) * 40 + hi * 8];
        #pragma unroll
        for (int f = 0; f < 16; ++f) {
            const bf16x8 bfv = *(const bf16x8*)&w1s[(f * 16 + ln15) * 40 + hi * 8];
            acc[f] = __builtin_amdgcn_mfma_f32_16x16x32_bf16(af, bfv, acc[f], 0, 0, 0);
        }
        __syncthreads();
    }

    // h1 = relu(acc + b1) -> LDS bf16 (aliases staging; all reads complete)
    #pragma unroll
    for (int f = 0; f < 16; ++f) {
        const int col = f * 16 + ln15;
        const float bias = b1[col];
        #pragma unroll
        for (int v = 0; v < 4; ++v) {
            const int r = m0 + hi * 4 + v;
            float val = acc[f][v] + bias;
            val = val > 0.f ? val : 0.f;
            h1s[r * 264 + col] = (short)f2bf(val);
        }
    }
    __syncthreads();

    // GEMM2: [64x256] @ [256x64]
    f32x4 acc2[4];
    #pragma unroll
    for (int f = 0; f < 4; ++f) acc2[f] = (f32x4){0.f, 0.f, 0.f, 0.f};

    #pragma unroll
    for (int kk = 0; kk < 8; ++kk) {
        const bf16x8 af = *(const bf16x8*)&h1s[(m0 + ln15) * 264 + kk * 32 + hi * 8];
        #pragma unroll
        for (int f = 0; f < 4; ++f) {
            const bf16x8 bfv = *(const bf16x8*)&w2s[(f * 16 + ln15) * 264 + kk * 32 + hi * 8];
            acc2[f] = __builtin_amdgcn_mfma_f32_16x16x32_bf16(af, bfv, acc2[f], 0, 0, 0);
        }
    }
    #pragma unroll
    for (int f = 0; f < 4; ++f) {
        const int col = f * 16 + ln15;
        const float bias = b2[col];
        #pragma unroll
        for (int v = 0; v < 4; ++v) {
            const long r = row0 + m0 + hi * 4 + v;
            if (r < n) h[r * C_DIM + col] = acc2[f][v] + bias;
        }
    }
}

// ---------------------------------------------------------------------------
// CSR build: histogram -> exclusive scan -> fill
// ---------------------------------------------------------------------------
__global__ void hist_kernel(const int* __restrict__ col, int* __restrict__ cnt, int e)
{
    int i = blockIdx.x * 256 + threadIdx.x;
    if (i < e) atomicAdd(&cnt[col[i]], 1);
}

__global__ void dinv_kernel(const int* __restrict__ cnt, float* __restrict__ dinv, int n)
{
    int i = blockIdx.x * 256 + threadIdx.x;
    if (i < n) dinv[i] = rsqrtf((float)cnt[i] + 1.0f);  // +1 self-loop
}

__global__ __launch_bounds__(256) void scan1_kernel(
    const int* __restrict__ cnt, int* __restrict__ rowptr, int* __restrict__ sums, int n)
{
    __shared__ int lds[256];
    const int t = threadIdx.x;
    const int base = blockIdx.x * 1024 + t * 4;
    int v[4];
    #pragma unroll
    for (int j = 0; j < 4; ++j) v[j] = (base + j < n) ? cnt[base + j] : 0;
    const int tsum = v[0] + v[1] + v[2] + v[3];
    lds[t] = tsum;
    __syncthreads();
    for (int o = 1; o < 256; o <<= 1) {
        const int add = (t >= o) ? lds[t - o] : 0;
        __syncthreads();
        lds[t] += add;
        __syncthreads();
    }
    int run = lds[t] - tsum;
    #pragma unroll
    for (int j = 0; j < 4; ++j) {
        if (base + j < n) rowptr[base + j] = run;
        run += v[j];
    }
    if (t == 255) sums[blockIdx.x] = lds[255];
}

__global__ __launch_bounds__(128) void scan2_kernel(int* __restrict__ sums, int nc)
{
    __shared__ int lds[128];
    const int t = threadIdx.x;
    const int v = (t < nc) ? sums[t] : 0;
    lds[t] = v;
    __syncthreads();
    for (int o = 1; o < 128; o <<= 1) {
        const int add = (t >= o) ? lds[t - o] : 0;
        __syncthreads();
        lds[t] += add;
        __syncthreads();
    }
    if (t < nc) sums[t] = lds[t] - v;
}

__global__ void scan3_kernel(int* __restrict__ rowptr, const int* __restrict__ sums, int n, int e)
{
    int i = blockIdx.x * 256 + threadIdx.x;
    if (i < n) rowptr[i] += sums[i >> 10];
    else if (i == n) rowptr[n] = e;
}

__global__ void fill_kernel(const int* __restrict__ row, const int* __restrict__ col,
                            const int* __restrict__ rowptr, int* __restrict__ cursor,
                            int* __restrict__ csr_src, int e)
{
    int i = blockIdx.x * 256 + threadIdx.x;
    if (i < e) {
        const int c = col[i];
        const int pos = rowptr[c] + atomicAdd(&cursor[c], 1);
        csr_src[pos] = row[i];
    }
}

// ---------------------------------------------------------------------------
// zs = bf16(h * dinv)
// ---------------------------------------------------------------------------
__global__ void zsinit_kernel(const float* __restrict__ h, const float* __restrict__ dinv,
                              ushort* __restrict__ zs, int n64)
{
    int i = blockIdx.x * 256 + threadIdx.x;
    if (i < n64) zs[i] = f2bf(h[i] * dinv[i >> 6]);
}

// ---------------------------------------------------------------------------
// Fused APPNP step (gather, bf16 state): one wave per node, lane = channel.
// Final iteration writes fp32 z in-place over h (element read by own thread only).
// ---------------------------------------------------------------------------
__global__ __launch_bounds__(256) void gather_kernel(
    const int* __restrict__ rowptr, const int* __restrict__ csr_src,
    const float* __restrict__ dinv, const float* h,
    const ushort* __restrict__ zs_in, ushort* __restrict__ zs_out,
    float* zfin, int n, int final_it)
{
    const int node = (blockIdx.x * 256 + threadIdx.x) >> 6;
    const int lane = threadIdx.x & 63;
    if (node >= n) return;

    const int p0 = rowptr[node];
    const int p1 = rowptr[node + 1];
    const long off = (long)node * C_DIM + lane;

    float acc = bf2f(zs_in[off]);  // self-loop
    int p = p0;
    for (; p + 4 <= p1; p += 4) {
        const int s0 = csr_src[p + 0];
        const int s1 = csr_src[p + 1];
        const int s2 = csr_src[p + 2];
        const int s3 = csr_src[p + 3];
        acc += bf2f(zs_in[(long)s0 * C_DIM + lane]);
        acc += bf2f(zs_in[(long)s1 * C_DIM + lane]);
        acc += bf2f(zs_in[(long)s2 * C_DIM + lane]);
        acc += bf2f(zs_in[(long)s3 * C_DIM + lane]);
    }
    for (; p < p1; ++p) acc += bf2f(zs_in[(long)csr_src[p] * C_DIM + lane]);

    const float di = dinv[node];
    const float znew = (1.0f - ALPHA) * (di * acc) + ALPHA * h[off];
    if (final_it) zfin[off] = znew;
    else          zs_out[off] = f2bf(znew * di);
}

// ---------------------------------------------------------------------------
// Row log-softmax over 64 channels: one wave per row
// ---------------------------------------------------------------------------
__global__ __launch_bounds__(256) void lsm_kernel(
    const float* __restrict__ z, float* __restrict__ out, int nrows)
{
    const int gid = blockIdx.x * 256 + threadIdx.x;
    const int rowi = gid >> 6;
    const int lane = threadIdx.x & 63;
    if (rowi < nrows) {
        const float v = z[(long)rowi * C_DIM + lane];
        float m = v;
        #pragma unroll
        for (int o = 32; o > 0; o >>= 1) m = fmaxf(m, __shfl_xor(m, o, 64));
        const float ex = expf(v - m);
        float s = ex;
        #pragma unroll
        for (int o = 32; o > 0; o >>= 1) s += __shfl_xor(s, o, 64);
        out[(long)rowi * C_DIM + lane] = v - m - logf(s);
    }
}

// ---------------------------------------------------------------------------
extern "C" void kernel_launch(void* const* d_in, const int* in_sizes, int n_in,
                              void* d_out, int out_size, void* d_ws, size_t ws_size,
                              hipStream_t stream)
{
    const float* x  = (const float*)d_in[0];
    const int* ei   = (const int*)d_in[1];
    const float* W1 = (const float*)d_in[2];
    const float* b1 = (const float*)d_in[3];
    const float* W2 = (const float*)d_in[4];
    const float* b2 = (const float*)d_in[5];
    float* out = (float*)d_out;

    const int N = in_sizes[0] / F_IN;       // 100000
    const int E = in_sizes[1] / 2;          // 3200000
    const int* row = ei;                    // source
    const int* col = ei + E;                // target

    // workspace layout
    char* ws = (char*)d_ws;
    float*  h      = (float*)ws;                              // N*64 f32
    ushort* zs_a   = (ushort*)(h + (long)N * C_DIM);          // N*64 bf16
    ushort* zs_b   = zs_a + (long)N * C_DIM;                  // N*64 bf16
    float*  dinv   = (float*)(zs_b + (long)N * C_DIM);        // N
    int*    cnt    = (int*)(dinv + N);                        // N
    int*    rowptr = cnt + N;                                 // N+1
    int*    cursor = rowptr + (N + 1);                        // N
    int*    sums   = cursor + N;                              // 128
    int*    csr_src = sums + 128;                             // E
    ushort* W1t    = (ushort*)(csr_src + E);                  // 512*256
    ushort* W2t    = W1t + 512 * 256;                         // 256*64

    const int nblk = (N + 255) / 256;
    const int eblk = (E + 255) / 256;
    const int nchunks = (N + 1023) / 1024;

    // 1. weight prep + MLP encoder
    prepW1_kernel<<<512, 256, 0, stream>>>(W1, W1t);
    prepW2_kernel<<<64, 256, 0, stream>>>(W2, W2t);
    mlp_mfma_kernel<<<(N + 63) / 64, 256, 0, stream>>>(x, W1t, b1, W2t, b2, h, N);

    // 2. CSR build + dinv
    hipMemsetAsync(cnt, 0, (size_t)N * sizeof(int), stream);
    hipMemsetAsync(cursor, 0, (size_t)N * sizeof(int), stream);
    hist_kernel<<<eblk, 256, 0, stream>>>(col, cnt, E);
    dinv_kernel<<<nblk, 256, 0, stream>>>(cnt, dinv, N);
    scan1_kernel<<<nchunks, 256, 0, stream>>>(cnt, rowptr, sums, N);
    scan2_kernel<<<1, 128, 0, stream>>>(sums, nchunks);
    scan3_kernel<<<(N + 256) / 256, 256, 0, stream>>>(rowptr, sums, N, E);
    fill_kernel<<<eblk, 256, 0, stream>>>(row, col, rowptr, cursor, csr_src, E);

    // 3. zs_a = bf16(h * dinv)
    zsinit_kernel<<<(N * C_DIM + 255) / 256, 256, 0, stream>>>(h, dinv, zs_a, N * C_DIM);

    // 4. APPNP iterations (ping-pong bf16; final iter writes fp32 into h)
    const int gblk = (N * C_DIM + 255) / 256;
    for (int it = 0; it < K_STEPS; ++it) {
        const ushort* in = (it & 1) ? zs_b : zs_a;
        ushort* outb     = (it & 1) ? zs_a : zs_b;
        gather_kernel<<<gblk, 256, 0, stream>>>(rowptr, csr_src, dinv, h,
                                                in, outb, h, N,
                                                it == K_STEPS - 1 ? 1 : 0);
    }

    // 5. log-softmax -> out
    lsm_kernel<<<(N * C_DIM + 255) / 256, 256, 0, stream>>>(h, out, N);
}

// Round 4
// 1135.308 us; speedup vs baseline: 7.0222x; 1.3236x over previous
//
#include <hip/hip_runtime.h>
#include <hip/hip_bf16.h>

#define F_IN 512
#define H_DIM 256
#define C_DIM 64
#define K_STEPS 10
#define ALPHA 0.1f

typedef __attribute__((ext_vector_type(8))) short bf16x8;
typedef __attribute__((ext_vector_type(4))) float f32x4;

static __device__ __forceinline__ ushort f2bf(float f) {
    __hip_bfloat16 b = __float2bfloat16(f);
    return *(ushort*)&b;
}
static __device__ __forceinline__ float bflo(unsigned int w) {
    union { unsigned int i; float f; } v; v.i = w << 16; return v.f;
}
static __device__ __forceinline__ float bfhi(unsigned int w) {
    union { unsigned int i; float f; } v; v.i = w & 0xffff0000u; return v.f;
}

// ---------------------------------------------------------------------------
// Weight prep: fragment-major bf16 layouts.
// W1p[(ks*16+f)*512 + lane*8 + j] = W1[ks*32 + (lane>>4)*8 + j][f*16 + (lane&15)]
// ---------------------------------------------------------------------------
__global__ void prepW1_kernel(const float* __restrict__ W1, ushort* __restrict__ W1p)
{
    const int o = blockIdx.x * 256 + threadIdx.x;   // 131072
    const int j = o & 7;
    const int l = (o >> 3) & 63;
    const int b = o >> 9;          // 0..255
    const int f = b & 15, ks = b >> 4;
    const int k = ks * 32 + (l >> 4) * 8 + j;
    const int col = f * 16 + (l & 15);
    W1p[o] = f2bf(W1[k * H_DIM + col]);
}

__global__ void prepW2_kernel(const float* __restrict__ W2, ushort* __restrict__ W2p)
{
    const int o = blockIdx.x * 256 + threadIdx.x;   // 16384
    const int j = o & 7;
    const int l = (o >> 3) & 63;
    const int b = o >> 9;          // 0..31
    const int f = b & 3, kk = b >> 2;
    const int k = kk * 32 + (l >> 4) * 8 + j;
    const int col = f * 16 + (l & 15);
    W2p[o] = f2bf(W2[k * C_DIM + col]);
}

// ---------------------------------------------------------------------------
// Fused MFMA MLP, barrier-free. Wave owns 16 rows; B-frags are coalesced
// 1KB global loads (L1/L2-hot); h1 exchanged via per-wave LDS tile.
// ---------------------------------------------------------------------------
__global__ __launch_bounds__(256) void mlp_mfma_kernel(
    const float* __restrict__ x,
    const ushort* __restrict__ W1p, const float* __restrict__ b1,
    const ushort* __restrict__ W2p, const float* __restrict__ b2,
    float* __restrict__ h, int n)
{
    __shared__ __align__(16) short h1s[4][16 * 264];   // 33792 B

    const int t = threadIdx.x;
    const int lane = t & 63;
    const int wv = t >> 6;
    const int ln15 = lane & 15;
    const int hi = lane >> 4;
    const long row0 = (long)blockIdx.x * 64 + wv * 16;

    long arow = row0 + ln15;
    if (arow > (long)n - 1) arow = n - 1;
    const float* xrow = x + arow * F_IN;

    f32x4 acc[16];
    #pragma unroll
    for (int f = 0; f < 16; ++f) acc[f] = (f32x4){0.f, 0.f, 0.f, 0.f};

    for (int ks = 0; ks < 16; ++ks) {
        const float4 a0 = *(const float4*)&xrow[ks * 32 + hi * 8];
        const float4 a1 = *(const float4*)&xrow[ks * 32 + hi * 8 + 4];
        bf16x8 af;
        af[0] = (short)f2bf(a0.x); af[1] = (short)f2bf(a0.y);
        af[2] = (short)f2bf(a0.z); af[3] = (short)f2bf(a0.w);
        af[4] = (short)f2bf(a1.x); af[5] = (short)f2bf(a1.y);
        af[6] = (short)f2bf(a1.z); af[7] = (short)f2bf(a1.w);
        const ushort* wb = W1p + (long)ks * 8192 + lane * 8;
        #pragma unroll
        for (int f = 0; f < 16; ++f) {
            const bf16x8 bfv = *(const bf16x8*)(wb + f * 512);
            acc[f] = __builtin_amdgcn_mfma_f32_16x16x32_bf16(af, bfv, acc[f], 0, 0, 0);
        }
    }

    // h1 = relu(acc + b1) -> per-wave LDS tile (no cross-wave access)
    short* hb = h1s[wv];
    #pragma unroll
    for (int f = 0; f < 16; ++f) {
        const int col = f * 16 + ln15;
        const float bias = b1[col];
        #pragma unroll
        for (int v = 0; v < 4; ++v) {
            float val = acc[f][v] + bias;
            val = val > 0.f ? val : 0.f;
            hb[(hi * 4 + v) * 264 + col] = (short)f2bf(val);
        }
    }

    // GEMM2: [16x256] @ [256x64]
    f32x4 acc2[4];
    #pragma unroll
    for (int f = 0; f < 4; ++f) acc2[f] = (f32x4){0.f, 0.f, 0.f, 0.f};
    #pragma unroll
    for (int kk = 0; kk < 8; ++kk) {
        const bf16x8 a2 = *(const bf16x8*)&hb[ln15 * 264 + kk * 32 + hi * 8];
        #pragma unroll
        for (int f = 0; f < 4; ++f) {
            const bf16x8 b2f = *(const bf16x8*)&W2p[(kk * 4 + f) * 512 + lane * 8];
            acc2[f] = __builtin_amdgcn_mfma_f32_16x16x32_bf16(a2, b2f, acc2[f], 0, 0, 0);
        }
    }
    #pragma unroll
    for (int f = 0; f < 4; ++f) {
        const int col = f * 16 + ln15;
        const float bias = b2[col];
        #pragma unroll
        for (int v = 0; v < 4; ++v) {
            const long r = row0 + hi * 4 + v;
            if (r < n) h[r * C_DIM + col] = acc2[f][v] + bias;
        }
    }
}

// ---------------------------------------------------------------------------
// CSR build: histogram -> exclusive scan -> fill
// ---------------------------------------------------------------------------
__global__ void hist_kernel(const int* __restrict__ col, int* __restrict__ cnt, int e)
{
    int i = blockIdx.x * 256 + threadIdx.x;
    if (i < e) atomicAdd(&cnt[col[i]], 1);
}

__global__ void dinv_kernel(const int* __restrict__ cnt, float* __restrict__ dinv, int n)
{
    int i = blockIdx.x * 256 + threadIdx.x;
    if (i < n) dinv[i] = rsqrtf((float)cnt[i] + 1.0f);  // +1 self-loop
}

__global__ __launch_bounds__(256) void scan1_kernel(
    const int* __restrict__ cnt, int* __restrict__ rowptr, int* __restrict__ sums, int n)
{
    __shared__ int lds[256];
    const int t = threadIdx.x;
    const int base = blockIdx.x * 1024 + t * 4;
    int v[4];
    #pragma unroll
    for (int j = 0; j < 4; ++j) v[j] = (base + j < n) ? cnt[base + j] : 0;
    const int tsum = v[0] + v[1] + v[2] + v[3];
    lds[t] = tsum;
    __syncthreads();
    for (int o = 1; o < 256; o <<= 1) {
        const int add = (t >= o) ? lds[t - o] : 0;
        __syncthreads();
        lds[t] += add;
        __syncthreads();
    }
    int run = lds[t] - tsum;
    #pragma unroll
    for (int j = 0; j < 4; ++j) {
        if (base + j < n) rowptr[base + j] = run;
        run += v[j];
    }
    if (t == 255) sums[blockIdx.x] = lds[255];
}

__global__ __launch_bounds__(128) void scan2_kernel(int* __restrict__ sums, int nc)
{
    __shared__ int lds[128];
    const int t = threadIdx.x;
    const int v = (t < nc) ? sums[t] : 0;
    lds[t] = v;
    __syncthreads();
    for (int o = 1; o < 128; o <<= 1) {
        const int add = (t >= o) ? lds[t - o] : 0;
        __syncthreads();
        lds[t] += add;
        __syncthreads();
    }
    if (t < nc) sums[t] = lds[t] - v;
}

__global__ void scan3_kernel(int* __restrict__ rowptr, const int* __restrict__ sums, int n, int e)
{
    int i = blockIdx.x * 256 + threadIdx.x;
    if (i < n) rowptr[i] += sums[i >> 10];
    else if (i == n) rowptr[n] = e;
}

__global__ void fill_kernel(const int* __restrict__ row, const int* __restrict__ col,
                            const int* __restrict__ rowptr, int* __restrict__ cursor,
                            int* __restrict__ csr_src, int e)
{
    int i = blockIdx.x * 256 + threadIdx.x;
    if (i < e) {
        const int c = col[i];
        const int pos = rowptr[c] + atomicAdd(&cursor[c], 1);
        csr_src[pos] = row[i];
    }
}

// ---------------------------------------------------------------------------
// zs = bf16(h * dinv), vectorized (16B stores)
// ---------------------------------------------------------------------------
__global__ void zsinit_kernel(const float* __restrict__ h, const float* __restrict__ dinv,
                              ushort* __restrict__ zs, int n)
{
    const int i = blockIdx.x * 256 + threadIdx.x;   // over n*8
    if (i >= n * 8) return;
    const int node = i >> 3, part = i & 7;
    const float di = dinv[node];
    const long off = (long)node * C_DIM + part * 8;
    const float4 ha = *(const float4*)&h[off];
    const float4 hb = *(const float4*)&h[off + 4];
    uint4 o;
    o.x = ((unsigned)f2bf(ha.y * di) << 16) | f2bf(ha.x * di);
    o.y = ((unsigned)f2bf(ha.w * di) << 16) | f2bf(ha.z * di);
    o.z = ((unsigned)f2bf(hb.y * di) << 16) | f2bf(hb.x * di);
    o.w = ((unsigned)f2bf(hb.w * di) << 16) | f2bf(hb.z * di);
    *(uint4*)&zs[off] = o;
}

// ---------------------------------------------------------------------------
// APPNP step, MLP-parallel gather: one wave per node, 8 edges in flight.
// lane = (slot s = lane>>3) x (channel-group cg = lane&7, 8 ch each).
// Virtual edge at p==p1 is the self-loop. shfl_xor reduce over slots.
// ---------------------------------------------------------------------------
__global__ __launch_bounds__(256) void gather8_kernel(
    const int* __restrict__ rowptr, const int* __restrict__ csr_src,
    const float* __restrict__ dinv, const float* __restrict__ hbuf,
    const ushort* __restrict__ zs_in, ushort* __restrict__ zs_out,
    float* __restrict__ zfin, int n, int final_it)
{
    const int node = (blockIdx.x * 256 + threadIdx.x) >> 6;
    if (node >= n) return;
    const int lane = threadIdx.x & 63;
    const int s = lane >> 3;
    const int cg = lane & 7;

    const int p0 = rowptr[node];
    const int p1 = rowptr[node + 1];   // virtual self slot at p == p1

    float acc[8];
    #pragma unroll
    for (int c = 0; c < 8; ++c) acc[c] = 0.f;

    for (int p = p0 + s; p <= p1; p += 8) {
        const int sp = (p < p1) ? p : 0;
        int idx = csr_src[sp];
        if (p >= p1) idx = node;
        const uint4 u = *(const uint4*)&zs_in[(long)idx * C_DIM + cg * 8];
        acc[0] += bflo(u.x); acc[1] += bfhi(u.x);
        acc[2] += bflo(u.y); acc[3] += bfhi(u.y);
        acc[4] += bflo(u.z); acc[5] += bfhi(u.z);
        acc[6] += bflo(u.w); acc[7] += bfhi(u.w);
    }

    #pragma unroll
    for (int c = 0; c < 8; ++c) {
        acc[c] += __shfl_xor(acc[c], 8, 64);
        acc[c] += __shfl_xor(acc[c], 16, 64);
        acc[c] += __shfl_xor(acc[c], 32, 64);
    }

    if (s == 0) {
        const float di = dinv[node];
        const long off = (long)node * C_DIM + cg * 8;
        const float4 ha = *(const float4*)&hbuf[off];
        const float4 hb = *(const float4*)&hbuf[off + 4];
        float z[8];
        z[0] = (1.0f - ALPHA) * (di * acc[0]) + ALPHA * ha.x;
        z[1] = (1.0f - ALPHA) * (di * acc[1]) + ALPHA * ha.y;
        z[2] = (1.0f - ALPHA) * (di * acc[2]) + ALPHA * ha.z;
        z[3] = (1.0f - ALPHA) * (di * acc[3]) + ALPHA * ha.w;
        z[4] = (1.0f - ALPHA) * (di * acc[4]) + ALPHA * hb.x;
        z[5] = (1.0f - ALPHA) * (di * acc[5]) + ALPHA * hb.y;
        z[6] = (1.0f - ALPHA) * (di * acc[6]) + ALPHA * hb.z;
        z[7] = (1.0f - ALPHA) * (di * acc[7]) + ALPHA * hb.w;
        if (final_it) {
            *(float4*)&zfin[off]     = make_float4(z[0], z[1], z[2], z[3]);
            *(float4*)&zfin[off + 4] = make_float4(z[4], z[5], z[6], z[7]);
        } else {
            uint4 o;
            o.x = ((unsigned)f2bf(z[1] * di) << 16) | f2bf(z[0] * di);
            o.y = ((unsigned)f2bf(z[3] * di) << 16) | f2bf(z[2] * di);
            o.z = ((unsigned)f2bf(z[5] * di) << 16) | f2bf(z[4] * di);
            o.w = ((unsigned)f2bf(z[7] * di) << 16) | f2bf(z[6] * di);
            *(uint4*)&zs_out[off] = o;
        }
    }
}

// ---------------------------------------------------------------------------
// Row log-softmax over 64 channels: one wave per row
// ---------------------------------------------------------------------------
__global__ __launch_bounds__(256) void lsm_kernel(
    const float* __restrict__ z, float* __restrict__ out, int nrows)
{
    const int gid = blockIdx.x * 256 + threadIdx.x;
    const int rowi = gid >> 6;
    const int lane = threadIdx.x & 63;
    if (rowi < nrows) {
        const float v = z[(long)rowi * C_DIM + lane];
        float m = v;
        #pragma unroll
        for (int o = 32; o > 0; o >>= 1) m = fmaxf(m, __shfl_xor(m, o, 64));
        const float ex = expf(v - m);
        float s = ex;
        #pragma unroll
        for (int o = 32; o > 0; o >>= 1) s += __shfl_xor(s, o, 64);
        out[(long)rowi * C_DIM + lane] = v - m - logf(s);
    }
}

// ---------------------------------------------------------------------------
extern "C" void kernel_launch(void* const* d_in, const int* in_sizes, int n_in,
                              void* d_out, int out_size, void* d_ws, size_t ws_size,
                              hipStream_t stream)
{
    const float* x  = (const float*)d_in[0];
    const int* ei   = (const int*)d_in[1];
    const float* W1 = (const float*)d_in[2];
    const float* b1 = (const float*)d_in[3];
    const float* W2 = (const float*)d_in[4];
    const float* b2 = (const float*)d_in[5];
    float* out = (float*)d_out;

    const int N = in_sizes[0] / F_IN;       // 100000
    const int E = in_sizes[1] / 2;          // 3200000
    const int* row = ei;                    // source
    const int* col = ei + E;                // target

    // workspace layout (all sub-buffers 16B-aligned)
    float*  h      = (float*)d_ws;                            // N*64 f32
    ushort* zs_a   = (ushort*)(h + (long)N * C_DIM);          // N*64 bf16
    ushort* zs_b   = zs_a + (long)N * C_DIM;                  // N*64 bf16
    float*  dinv   = (float*)(zs_b + (long)N * C_DIM);        // N
    int*    cnt    = (int*)(dinv + N);                        // N
    int*    rowptr = cnt + N;                                 // N+16 (padded)
    int*    cursor = rowptr + N + 16;                         // N
    int*    sums   = cursor + N;                              // 128
    int*    csr_src = sums + 128;                             // E
    ushort* W1p    = (ushort*)(csr_src + E);                  // 131072
    ushort* W2p    = W1p + 131072;                            // 16384

    const int nblk = (N + 255) / 256;
    const int eblk = (E + 255) / 256;
    const int nchunks = (N + 1023) / 1024;

    // 1. weight prep + MLP encoder
    prepW1_kernel<<<512, 256, 0, stream>>>(W1, W1p);
    prepW2_kernel<<<64, 256, 0, stream>>>(W2, W2p);
    mlp_mfma_kernel<<<(N + 63) / 64, 256, 0, stream>>>(x, W1p, b1, W2p, b2, h, N);

    // 2. CSR build + dinv
    hipMemsetAsync(cnt, 0, (size_t)N * sizeof(int), stream);
    hipMemsetAsync(cursor, 0, (size_t)N * sizeof(int), stream);
    hist_kernel<<<eblk, 256, 0, stream>>>(col, cnt, E);
    dinv_kernel<<<nblk, 256, 0, stream>>>(cnt, dinv, N);
    scan1_kernel<<<nchunks, 256, 0, stream>>>(cnt, rowptr, sums, N);
    scan2_kernel<<<1, 128, 0, stream>>>(sums, nchunks);
    scan3_kernel<<<(N + 256) / 256, 256, 0, stream>>>(rowptr, sums, N, E);
    fill_kernel<<<eblk, 256, 0, stream>>>(row, col, rowptr, cursor, csr_src, E);

    // 3. zs_a = bf16(h * dinv)
    zsinit_kernel<<<(N * 8 + 255) / 256, 256, 0, stream>>>(h, dinv, zs_a, N);

    // 4. APPNP iterations (ping-pong bf16; final iter writes fp32 into h)
    const int gblk = (N + 3) / 4;   // one wave per node
    for (int it = 0; it < K_STEPS; ++it) {
        const ushort* in = (it & 1) ? zs_b : zs_a;
        ushort* outb     = (it & 1) ? zs_a : zs_b;
        gather8_kernel<<<gblk, 256, 0, stream>>>(rowptr, csr_src, dinv, h,
                                                 in, outb, h, N,
                                                 it == K_STEPS - 1 ? 1 : 0);
    }

    // 5. log-softmax -> out
    lsm_kernel<<<(N * C_DIM + 255) / 256, 256, 0, stream>>>(h, out, N);
}

// Round 5
// 947.526 us; speedup vs baseline: 8.4139x; 1.1982x over previous
//
#include <hip/hip_runtime.h>
#include <hip/hip_bf16.h>

#define F_IN 512
#define H_DIM 256
#define C_DIM 64
#define K_STEPS 10
#define ALPHA 0.1f

typedef __attribute__((ext_vector_type(8))) short bf16x8;
typedef __attribute__((ext_vector_type(4))) float f32x4;

static __device__ __forceinline__ ushort f2bf(float f) {
    __hip_bfloat16 b = __float2bfloat16(f);
    return *(ushort*)&b;
}
static __device__ __forceinline__ float bflo(unsigned int w) {
    union { unsigned int i; float f; } v; v.i = w << 16; return v.f;
}
static __device__ __forceinline__ float bfhi(unsigned int w) {
    union { unsigned int i; float f; } v; v.i = w & 0xffff0000u; return v.f;
}

#define ACC8(u) do { \
    acc[0] += bflo(u.x); acc[1] += bfhi(u.x); \
    acc[2] += bflo(u.y); acc[3] += bfhi(u.y); \
    acc[4] += bflo(u.z); acc[5] += bfhi(u.z); \
    acc[6] += bflo(u.w); acc[7] += bfhi(u.w); } while (0)

// ---------------------------------------------------------------------------
// Prep: W1/W2 -> fragment-major bf16 + zero cnt. One launch, 131072 threads.
// W1p[(ks*16+f)*512 + lane*8 + j] = W1[ks*32 + (lane>>4)*8 + j][f*16 + (lane&15)]
// ---------------------------------------------------------------------------
__global__ void prep_kernel(const float* __restrict__ W1, ushort* __restrict__ W1p,
                            const float* __restrict__ W2, ushort* __restrict__ W2p,
                            int* __restrict__ cnt, int n)
{
    const int o = blockIdx.x * 256 + threadIdx.x;
    {   // W1p: o in [0, 131072)
        const int j = o & 7;
        const int l = (o >> 3) & 63;
        const int b = o >> 9;          // 0..255
        const int f = b & 15, ks = b >> 4;
        const int k = ks * 32 + (l >> 4) * 8 + j;
        const int col = f * 16 + (l & 15);
        W1p[o] = f2bf(W1[k * H_DIM + col]);
    }
    if (o < 16384) {
        const int j = o & 7;
        const int l = (o >> 3) & 63;
        const int b = o >> 9;          // 0..31
        const int f = b & 3, kk = b >> 2;
        const int k = kk * 32 + (l >> 4) * 8 + j;
        const int col = f * 16 + (l & 15);
        W2p[o] = f2bf(W2[k * C_DIM + col]);
    }
    if (o < n) cnt[o] = 0;
}

// ---------------------------------------------------------------------------
// Rank pass: the ONLY atomic pass. rank[i] = arrival order at target col[i].
// ---------------------------------------------------------------------------
__global__ void rank_kernel(const int* __restrict__ col, int* __restrict__ cnt,
                            int* __restrict__ rank, int e)
{
    int i = blockIdx.x * 256 + threadIdx.x;
    if (i < e) rank[i] = atomicAdd(&cnt[col[i]], 1);
}

// ---------------------------------------------------------------------------
// Scan (1024 elems/block) + dinv fused
// ---------------------------------------------------------------------------
__global__ __launch_bounds__(256) void scan1_kernel(
    const int* __restrict__ cnt, int* __restrict__ rowptr, int* __restrict__ sums,
    float* __restrict__ dinv, int n)
{
    __shared__ int lds[256];
    const int t = threadIdx.x;
    const int base = blockIdx.x * 1024 + t * 4;
    int v[4];
    #pragma unroll
    for (int j = 0; j < 4; ++j) v[j] = (base + j < n) ? cnt[base + j] : 0;
    const int tsum = v[0] + v[1] + v[2] + v[3];
    lds[t] = tsum;
    __syncthreads();
    for (int o = 1; o < 256; o <<= 1) {
        const int add = (t >= o) ? lds[t - o] : 0;
        __syncthreads();
        lds[t] += add;
        __syncthreads();
    }
    int run = lds[t] - tsum;
    #pragma unroll
    for (int j = 0; j < 4; ++j) {
        if (base + j < n) {
            rowptr[base + j] = run;
            dinv[base + j] = rsqrtf((float)v[j] + 1.0f);   // +1 self-loop
        }
        run += v[j];
    }
    if (t == 255) sums[blockIdx.x] = lds[255];
}

__global__ __launch_bounds__(128) void scan2_kernel(int* __restrict__ sums, int nc)
{
    __shared__ int lds[128];
    const int t = threadIdx.x;
    const int v = (t < nc) ? sums[t] : 0;
    lds[t] = v;
    __syncthreads();
    for (int o = 1; o < 128; o <<= 1) {
        const int add = (t >= o) ? lds[t - o] : 0;
        __syncthreads();
        lds[t] += add;
        __syncthreads();
    }
    if (t < nc) sums[t] = lds[t] - v;
}

__global__ void scan3_kernel(int* __restrict__ rowptr, const int* __restrict__ sums, int n, int e)
{
    int i = blockIdx.x * 256 + threadIdx.x;
    if (i < n) rowptr[i] += sums[i >> 10];
    else if (i == n) rowptr[n] = e;
}

// ---------------------------------------------------------------------------
// Atomic-free fill
// ---------------------------------------------------------------------------
__global__ void fill_kernel(const int* __restrict__ row, const int* __restrict__ col,
                            const int* __restrict__ rowptr, const int* __restrict__ rank,
                            int* __restrict__ csr_src, int e)
{
    int i = blockIdx.x * 256 + threadIdx.x;
    if (i < e) csr_src[rowptr[col[i]] + rank[i]] = row[i];
}

// ---------------------------------------------------------------------------
// Fused MFMA MLP + zs init. Wave owns 16 rows; barrier-free; per-wave LDS tile.
// Epilogue writes h (f32) and zs = bf16(h*dinv).
// ---------------------------------------------------------------------------
__global__ __launch_bounds__(256) void mlp_mfma_kernel(
    const float* __restrict__ x,
    const ushort* __restrict__ W1p, const float* __restrict__ b1,
    const ushort* __restrict__ W2p, const float* __restrict__ b2,
    const float* __restrict__ dinv,
    float* __restrict__ h, ushort* __restrict__ zs, int n)
{
    __shared__ __align__(16) short h1s[4][16 * 264];   // 33792 B

    const int t = threadIdx.x;
    const int lane = t & 63;
    const int wv = t >> 6;
    const int ln15 = lane & 15;
    const int hi = lane >> 4;
    const long row0 = (long)blockIdx.x * 64 + wv * 16;

    long arow = row0 + ln15;
    if (arow > (long)n - 1) arow = n - 1;
    const float* xrow = x + arow * F_IN;

    f32x4 acc[16];
    #pragma unroll
    for (int f = 0; f < 16; ++f) acc[f] = (f32x4){0.f, 0.f, 0.f, 0.f};

    for (int ks = 0; ks < 16; ++ks) {
        const float4 a0 = *(const float4*)&xrow[ks * 32 + hi * 8];
        const float4 a1 = *(const float4*)&xrow[ks * 32 + hi * 8 + 4];
        bf16x8 af;
        af[0] = (short)f2bf(a0.x); af[1] = (short)f2bf(a0.y);
        af[2] = (short)f2bf(a0.z); af[3] = (short)f2bf(a0.w);
        af[4] = (short)f2bf(a1.x); af[5] = (short)f2bf(a1.y);
        af[6] = (short)f2bf(a1.z); af[7] = (short)f2bf(a1.w);
        const ushort* wb = W1p + (long)ks * 8192 + lane * 8;
        #pragma unroll
        for (int f = 0; f < 16; ++f) {
            const bf16x8 bfv = *(const bf16x8*)(wb + f * 512);
            acc[f] = __builtin_amdgcn_mfma_f32_16x16x32_bf16(af, bfv, acc[f], 0, 0, 0);
        }
    }

    short* hb = h1s[wv];
    #pragma unroll
    for (int f = 0; f < 16; ++f) {
        const int col = f * 16 + ln15;
        const float bias = b1[col];
        #pragma unroll
        for (int v = 0; v < 4; ++v) {
            float val = acc[f][v] + bias;
            val = val > 0.f ? val : 0.f;
            hb[(hi * 4 + v) * 264 + col] = (short)f2bf(val);
        }
    }

    f32x4 acc2[4];
    #pragma unroll
    for (int f = 0; f < 4; ++f) acc2[f] = (f32x4){0.f, 0.f, 0.f, 0.f};
    #pragma unroll
    for (int kk = 0; kk < 8; ++kk) {
        const bf16x8 a2 = *(const bf16x8*)&hb[ln15 * 264 + kk * 32 + hi * 8];
        #pragma unroll
        for (int f = 0; f < 4; ++f) {
            const bf16x8 b2f = *(const bf16x8*)&W2p[(kk * 4 + f) * 512 + lane * 8];
            acc2[f] = __builtin_amdgcn_mfma_f32_16x16x32_bf16(a2, b2f, acc2[f], 0, 0, 0);
        }
    }

    float di4[4];
    #pragma unroll
    for (int v = 0; v < 4; ++v) {
        const long r = row0 + hi * 4 + v;
        di4[v] = (r < n) ? dinv[r] : 0.f;
    }
    #pragma unroll
    for (int f = 0; f < 4; ++f) {
        const int col = f * 16 + ln15;
        const float bias = b2[col];
        #pragma unroll
        for (int v = 0; v < 4; ++v) {
            const long r = row0 + hi * 4 + v;
            if (r < n) {
                const float val = acc2[f][v] + bias;
                h[r * C_DIM + col] = val;
                zs[r * C_DIM + col] = f2bf(val * di4[v]);
            }
        }
    }
}

// ---------------------------------------------------------------------------
// APPNP step: one wave per node, 8 edges in flight, 2x unrolled.
// lane = (slot s = lane>>3) x (channel-group cg = lane&7).
// Self-loop hoisted. Final iteration fuses log-softmax and writes d_out.
// ---------------------------------------------------------------------------
__global__ __launch_bounds__(256) void gather8_kernel(
    const int* __restrict__ rowptr, const int* __restrict__ csr_src,
    const float* __restrict__ dinv, const float* __restrict__ hbuf,
    const ushort* __restrict__ zs_in, ushort* __restrict__ zs_out,
    float* __restrict__ out, int n, int final_it)
{
    const int node = (blockIdx.x * 256 + threadIdx.x) >> 6;
    if (node >= n) return;
    const int lane = threadIdx.x & 63;
    const int s = lane >> 3;
    const int cg = lane & 7;

    const int p0 = rowptr[node];
    const int p1 = rowptr[node + 1];

    float acc[8];
    #pragma unroll
    for (int c = 0; c < 8; ++c) acc[c] = 0.f;

    if (s == 0) {  // self-loop: 8 lanes cover own 128B row
        const uint4 u = *(const uint4*)&zs_in[(long)node * C_DIM + cg * 8];
        ACC8(u);
    }

    int p = p0 + s;
    for (; p + 8 < p1; p += 16) {
        const int i0 = csr_src[p];
        const int i1 = csr_src[p + 8];
        const uint4 u0 = *(const uint4*)&zs_in[(long)i0 * C_DIM + cg * 8];
        const uint4 u1 = *(const uint4*)&zs_in[(long)i1 * C_DIM + cg * 8];
        ACC8(u0);
        ACC8(u1);
    }
    if (p < p1) {
        const int i0 = csr_src[p];
        const uint4 u0 = *(const uint4*)&zs_in[(long)i0 * C_DIM + cg * 8];
        ACC8(u0);
    }

    #pragma unroll
    for (int c = 0; c < 8; ++c) {
        acc[c] += __shfl_xor(acc[c], 8, 64);
        acc[c] += __shfl_xor(acc[c], 16, 64);
        acc[c] += __shfl_xor(acc[c], 32, 64);
    }

    if (s == 0) {
        const float di = dinv[node];
        const long off = (long)node * C_DIM + cg * 8;
        const float4 ha = *(const float4*)&hbuf[off];
        const float4 hb = *(const float4*)&hbuf[off + 4];
        float z[8];
        z[0] = (1.0f - ALPHA) * (di * acc[0]) + ALPHA * ha.x;
        z[1] = (1.0f - ALPHA) * (di * acc[1]) + ALPHA * ha.y;
        z[2] = (1.0f - ALPHA) * (di * acc[2]) + ALPHA * ha.z;
        z[3] = (1.0f - ALPHA) * (di * acc[3]) + ALPHA * ha.w;
        z[4] = (1.0f - ALPHA) * (di * acc[4]) + ALPHA * hb.x;
        z[5] = (1.0f - ALPHA) * (di * acc[5]) + ALPHA * hb.y;
        z[6] = (1.0f - ALPHA) * (di * acc[6]) + ALPHA * hb.z;
        z[7] = (1.0f - ALPHA) * (di * acc[7]) + ALPHA * hb.w;
        if (!final_it) {
            uint4 o;
            o.x = ((unsigned)f2bf(z[1] * di) << 16) | f2bf(z[0] * di);
            o.y = ((unsigned)f2bf(z[3] * di) << 16) | f2bf(z[2] * di);
            o.z = ((unsigned)f2bf(z[5] * di) << 16) | f2bf(z[4] * di);
            o.w = ((unsigned)f2bf(z[7] * di) << 16) | f2bf(z[6] * di);
            *(uint4*)&zs_out[off] = o;
        } else {
            // fused log-softmax across the 8 lanes (s==0, cg=0..7) of this node
            float m = z[0];
            #pragma unroll
            for (int j = 1; j < 8; ++j) m = fmaxf(m, z[j]);
            m = fmaxf(m, __shfl_xor(m, 1, 64));
            m = fmaxf(m, __shfl_xor(m, 2, 64));
            m = fmaxf(m, __shfl_xor(m, 4, 64));
            float se = 0.f;
            #pragma unroll
            for (int j = 0; j < 8; ++j) se += expf(z[j] - m);
            se += __shfl_xor(se, 1, 64);
            se += __shfl_xor(se, 2, 64);
            se += __shfl_xor(se, 4, 64);
            const float ls = m + logf(se);
            *(float4*)&out[off]     = make_float4(z[0] - ls, z[1] - ls, z[2] - ls, z[3] - ls);
            *(float4*)&out[off + 4] = make_float4(z[4] - ls, z[5] - ls, z[6] - ls, z[7] - ls);
        }
    }
}

// ---------------------------------------------------------------------------
extern "C" void kernel_launch(void* const* d_in, const int* in_sizes, int n_in,
                              void* d_out, int out_size, void* d_ws, size_t ws_size,
                              hipStream_t stream)
{
    const float* x  = (const float*)d_in[0];
    const int* ei   = (const int*)d_in[1];
    const float* W1 = (const float*)d_in[2];
    const float* b1 = (const float*)d_in[3];
    const float* W2 = (const float*)d_in[4];
    const float* b2 = (const float*)d_in[5];
    float* out = (float*)d_out;

    const int N = in_sizes[0] / F_IN;       // 100000
    const int E = in_sizes[1] / 2;          // 3200000
    const int* row = ei;                    // source
    const int* col = ei + E;                // target

    // workspace layout
    float*  h      = (float*)d_ws;                            // N*64 f32
    ushort* zs_a   = (ushort*)(h + (long)N * C_DIM);          // N*64 bf16
    ushort* zs_b   = zs_a + (long)N * C_DIM;                  // N*64 bf16
    float*  dinv   = (float*)(zs_b + (long)N * C_DIM);        // N
    int*    cnt    = (int*)(dinv + N);                        // N
    int*    rowptr = cnt + N;                                 // N+16 (padded)
    int*    rank   = rowptr + N + 16;                         // E
    int*    csr_src = rank + E;                               // E
    int*    sums   = csr_src + E;                             // 128
    ushort* W1p    = (ushort*)(sums + 128);                   // 131072
    ushort* W2p    = W1p + 131072;                            // 16384

    const int eblk = (E + 255) / 256;
    const int nchunks = (N + 1023) / 1024;

    // 1. weight prep + cnt zero
    prep_kernel<<<512, 256, 0, stream>>>(W1, W1p, W2, W2p, cnt, N);

    // 2. CSR build (one atomic pass)
    rank_kernel<<<eblk, 256, 0, stream>>>(col, cnt, rank, E);
    scan1_kernel<<<nchunks, 256, 0, stream>>>(cnt, rowptr, sums, dinv, N);
    scan2_kernel<<<1, 128, 0, stream>>>(sums, nchunks);
    scan3_kernel<<<(N + 256) / 256, 256, 0, stream>>>(rowptr, sums, N, E);
    fill_kernel<<<eblk, 256, 0, stream>>>(row, col, rowptr, rank, csr_src, E);

    // 3. MLP encoder (+ zs_a = bf16(h*dinv))
    mlp_mfma_kernel<<<(N + 63) / 64, 256, 0, stream>>>(x, W1p, b1, W2p, b2,
                                                       dinv, h, zs_a, N);

    // 4. APPNP iterations (ping-pong bf16; final fuses log-softmax -> out)
    const int gblk = (N + 3) / 4;   // one wave per node
    for (int it = 0; it < K_STEPS; ++it) {
        const ushort* in = (it & 1) ? zs_b : zs_a;
        ushort* outb     = (it & 1) ? zs_a : zs_b;
        gather8_kernel<<<gblk, 256, 0, stream>>>(rowptr, csr_src, dinv, h,
                                                 in, outb, out, N,
                                                 it == K_STEPS - 1 ? 1 : 0);
    }
}

// Round 6
// 905.654 us; speedup vs baseline: 8.8029x; 1.0462x over previous
//
#include <hip/hip_runtime.h>
#include <hip/hip_bf16.h>

#define F_IN 512
#define H_DIM 256
#define C_DIM 64
#define K_STEPS 10
#define ALPHA 0.1f

typedef __attribute__((ext_vector_type(8))) short bf16x8;
typedef __attribute__((ext_vector_type(4))) float f32x4;

static __device__ __forceinline__ ushort f2bf(float f) {
    __hip_bfloat16 b = __float2bfloat16(f);
    return *(ushort*)&b;
}
static __device__ __forceinline__ float bflo(unsigned int w) {
    union { unsigned int i; float f; } v; v.i = w << 16; return v.f;
}
static __device__ __forceinline__ float bfhi(unsigned int w) {
    union { unsigned int i; float f; } v; v.i = w & 0xffff0000u; return v.f;
}

#define ACC8(u) do { \
    acc[0] += bflo(u.x); acc[1] += bfhi(u.x); \
    acc[2] += bflo(u.y); acc[3] += bfhi(u.y); \
    acc[4] += bflo(u.z); acc[5] += bfhi(u.z); \
    acc[6] += bflo(u.w); acc[7] += bfhi(u.w); } while (0)

// ---------------------------------------------------------------------------
// Prep: W1/W2 -> fragment-major bf16 + zero cnt. One launch, 131072 threads.
// ---------------------------------------------------------------------------
__global__ void prep_kernel(const float* __restrict__ W1, ushort* __restrict__ W1p,
                            const float* __restrict__ W2, ushort* __restrict__ W2p,
                            int* __restrict__ cnt, int n)
{
    const int o = blockIdx.x * 256 + threadIdx.x;
    {   // W1p: o in [0, 131072)
        const int j = o & 7;
        const int l = (o >> 3) & 63;
        const int b = o >> 9;          // 0..255
        const int f = b & 15, ks = b >> 4;
        const int k = ks * 32 + (l >> 4) * 8 + j;
        const int col = f * 16 + (l & 15);
        W1p[o] = f2bf(W1[k * H_DIM + col]);
    }
    if (o < 16384) {
        const int j = o & 7;
        const int l = (o >> 3) & 63;
        const int b = o >> 9;          // 0..31
        const int f = b & 3, kk = b >> 2;
        const int k = kk * 32 + (l >> 4) * 8 + j;
        const int col = f * 16 + (l & 15);
        W2p[o] = f2bf(W2[k * C_DIM + col]);
    }
    if (o < n) cnt[o] = 0;
}

// ---------------------------------------------------------------------------
// Rank pass: the ONLY atomic pass. rank[i] = arrival order at target col[i].
// ---------------------------------------------------------------------------
__global__ void rank_kernel(const int* __restrict__ col, int* __restrict__ cnt,
                            int* __restrict__ rank, int e)
{
    int i = blockIdx.x * 256 + threadIdx.x;
    if (i < e) rank[i] = atomicAdd(&cnt[col[i]], 1);
}

// ---------------------------------------------------------------------------
// Scan (1024 elems/block) + dinv fused
// ---------------------------------------------------------------------------
__global__ __launch_bounds__(256) void scan1_kernel(
    const int* __restrict__ cnt, int* __restrict__ rowptr, int* __restrict__ sums,
    float* __restrict__ dinv, int n)
{
    __shared__ int lds[256];
    const int t = threadIdx.x;
    const int base = blockIdx.x * 1024 + t * 4;
    int v[4];
    #pragma unroll
    for (int j = 0; j < 4; ++j) v[j] = (base + j < n) ? cnt[base + j] : 0;
    const int tsum = v[0] + v[1] + v[2] + v[3];
    lds[t] = tsum;
    __syncthreads();
    for (int o = 1; o < 256; o <<= 1) {
        const int add = (t >= o) ? lds[t - o] : 0;
        __syncthreads();
        lds[t] += add;
        __syncthreads();
    }
    int run = lds[t] - tsum;
    #pragma unroll
    for (int j = 0; j < 4; ++j) {
        if (base + j < n) {
            rowptr[base + j] = run;
            dinv[base + j] = rsqrtf((float)v[j] + 1.0f);   // +1 self-loop
        }
        run += v[j];
    }
    if (t == 255) sums[blockIdx.x] = lds[255];
}

__global__ __launch_bounds__(128) void scan2_kernel(int* __restrict__ sums, int nc)
{
    __shared__ int lds[128];
    const int t = threadIdx.x;
    const int v = (t < nc) ? sums[t] : 0;
    lds[t] = v;
    __syncthreads();
    for (int o = 1; o < 128; o <<= 1) {
        const int add = (t >= o) ? lds[t - o] : 0;
        __syncthreads();
        lds[t] += add;
        __syncthreads();
    }
    if (t < nc) sums[t] = lds[t] - v;
}

__global__ void scan3_kernel(int* __restrict__ rowptr, const int* __restrict__ sums, int n, int e)
{
    int i = blockIdx.x * 256 + threadIdx.x;
    if (i < n) rowptr[i] += sums[i >> 10];
    else if (i == n) rowptr[n] = e;
}

// ---------------------------------------------------------------------------
// Atomic-free fill
// ---------------------------------------------------------------------------
__global__ void fill_kernel(const int* __restrict__ row, const int* __restrict__ col,
                            const int* __restrict__ rowptr, const int* __restrict__ rank,
                            int* __restrict__ csr_src, int e)
{
    int i = blockIdx.x * 256 + threadIdx.x;
    if (i < e) csr_src[rowptr[col[i]] + rank[i]] = row[i];
}

// ---------------------------------------------------------------------------
// Fused MFMA MLP. Wave owns 16 rows; barrier-free; per-wave LDS tile.
// x loads software-pipelined depth 2 (fully unrolled ks -> static xb[] idx).
// Epilogue writes zs = bf16(h*dinv) and ah = bf16(ALPHA*h).
// ---------------------------------------------------------------------------
__global__ __launch_bounds__(256) void mlp_mfma_kernel(
    const float* __restrict__ x,
    const ushort* __restrict__ W1p, const float* __restrict__ b1,
    const ushort* __restrict__ W2p, const float* __restrict__ b2,
    const float* __restrict__ dinv,
    ushort* __restrict__ ah, ushort* __restrict__ zs, int n)
{
    __shared__ __align__(16) short h1s[4][16 * 264];   // 33792 B

    const int t = threadIdx.x;
    const int lane = t & 63;
    const int wv = t >> 6;
    const int ln15 = lane & 15;
    const int hi = lane >> 4;
    const long row0 = (long)blockIdx.x * 64 + wv * 16;

    long arow = row0 + ln15;
    if (arow > (long)n - 1) arow = n - 1;
    const float4* xp = (const float4*)(x + arow * F_IN);

    f32x4 acc[16];
    #pragma unroll
    for (int f = 0; f < 16; ++f) acc[f] = (f32x4){0.f, 0.f, 0.f, 0.f};

    // prologue: prefetch ks=0,1
    float4 xb[2][2];
    xb[0][0] = xp[hi * 2];     xb[0][1] = xp[hi * 2 + 1];
    xb[1][0] = xp[8 + hi * 2]; xb[1][1] = xp[8 + hi * 2 + 1];

    #pragma unroll
    for (int ks = 0; ks < 16; ++ks) {
        const int sl = ks & 1;
        const float4 a0 = xb[sl][0];
        const float4 a1 = xb[sl][1];
        if (ks + 2 < 16) {   // prefetch ks+2 into freed slot
            xb[sl][0] = xp[(ks + 2) * 8 + hi * 2];
            xb[sl][1] = xp[(ks + 2) * 8 + hi * 2 + 1];
        }
        bf16x8 af;
        af[0] = (short)f2bf(a0.x); af[1] = (short)f2bf(a0.y);
        af[2] = (short)f2bf(a0.z); af[3] = (short)f2bf(a0.w);
        af[4] = (short)f2bf(a1.x); af[5] = (short)f2bf(a1.y);
        af[6] = (short)f2bf(a1.z); af[7] = (short)f2bf(a1.w);
        const ushort* wb = W1p + (long)ks * 8192 + lane * 8;
        #pragma unroll
        for (int f = 0; f < 16; ++f) {
            const bf16x8 bfv = *(const bf16x8*)(wb + f * 512);
            acc[f] = __builtin_amdgcn_mfma_f32_16x16x32_bf16(af, bfv, acc[f], 0, 0, 0);
        }
    }

    short* hb = h1s[wv];
    #pragma unroll
    for (int f = 0; f < 16; ++f) {
        const int col = f * 16 + ln15;
        const float bias = b1[col];
        #pragma unroll
        for (int v = 0; v < 4; ++v) {
            float val = acc[f][v] + bias;
            val = val > 0.f ? val : 0.f;
            hb[(hi * 4 + v) * 264 + col] = (short)f2bf(val);
        }
    }

    f32x4 acc2[4];
    #pragma unroll
    for (int f = 0; f < 4; ++f) acc2[f] = (f32x4){0.f, 0.f, 0.f, 0.f};
    #pragma unroll
    for (int kk = 0; kk < 8; ++kk) {
        const bf16x8 a2 = *(const bf16x8*)&hb[ln15 * 264 + kk * 32 + hi * 8];
        #pragma unroll
        for (int f = 0; f < 4; ++f) {
            const bf16x8 b2f = *(const bf16x8*)&W2p[(kk * 4 + f) * 512 + lane * 8];
            acc2[f] = __builtin_amdgcn_mfma_f32_16x16x32_bf16(a2, b2f, acc2[f], 0, 0, 0);
        }
    }

    float di4[4];
    #pragma unroll
    for (int v = 0; v < 4; ++v) {
        const long r = row0 + hi * 4 + v;
        di4[v] = (r < n) ? dinv[r] : 0.f;
    }
    #pragma unroll
    for (int f = 0; f < 4; ++f) {
        const int col = f * 16 + ln15;
        const float bias = b2[col];
        #pragma unroll
        for (int v = 0; v < 4; ++v) {
            const long r = row0 + hi * 4 + v;
            if (r < n) {
                const float val = acc2[f][v] + bias;
                ah[r * C_DIM + col] = f2bf(ALPHA * val);
                zs[r * C_DIM + col] = f2bf(val * di4[v]);
            }
        }
    }
}

// ---------------------------------------------------------------------------
// APPNP step: one wave per node; slot s = lane>>3 (8 edges in flight),
// channel-group cg = lane&7. Two-stage pipeline: indices one iteration
// ahead, rows double-buffered. Final iteration fuses log-softmax.
// ---------------------------------------------------------------------------
__global__ __launch_bounds__(256) void gather8_kernel(
    const int* __restrict__ rowptr, const int* __restrict__ csr_src,
    const float* __restrict__ dinv, const ushort* __restrict__ ah,
    const ushort* __restrict__ zs_in, ushort* __restrict__ zs_out,
    float* __restrict__ out, int n, int final_it)
{
    const int node = (blockIdx.x * 256 + threadIdx.x) >> 6;
    if (node >= n) return;
    const int lane = threadIdx.x & 63;
    const int s = lane >> 3;
    const int cg = lane & 7;

    const int p0 = rowptr[node];
    const int p1 = rowptr[node + 1];

    float acc[8];
    #pragma unroll
    for (int c = 0; c < 8; ++c) acc[c] = 0.f;

    if (s == 0) {  // self-loop: 8 lanes cover own 128B row
        const uint4 u = *(const uint4*)&zs_in[(long)node * C_DIM + cg * 8];
        ACC8(u);
    }

    if (p0 < p1) {
        int p = p0 + s;
        int c0 = (p     < p1) ? csr_src[p]     : -1;
        int c1 = (p + 8 < p1) ? csr_src[p + 8] : -1;
        while (c0 >= 0) {
            uint4 u0, u1;
            u0 = *(const uint4*)&zs_in[(long)c0 * C_DIM + cg * 8];
            if (c1 >= 0) u1 = *(const uint4*)&zs_in[(long)c1 * C_DIM + cg * 8];
            const int np = p + 16;
            const int n0 = (np     < p1) ? csr_src[np]     : -1;
            const int n1 = (np + 8 < p1) ? csr_src[np + 8] : -1;
            ACC8(u0);
            if (c1 >= 0) ACC8(u1);
            c0 = n0; c1 = n1; p = np;
        }
    }

    #pragma unroll
    for (int c = 0; c < 8; ++c) {
        acc[c] += __shfl_xor(acc[c], 8, 64);
        acc[c] += __shfl_xor(acc[c], 16, 64);
        acc[c] += __shfl_xor(acc[c], 32, 64);
    }

    if (s == 0) {
        const float di = dinv[node];
        const long off = (long)node * C_DIM + cg * 8;
        const uint4 ua = *(const uint4*)&ah[off];
        const float w = (1.0f - ALPHA) * di;
        float z[8];
        z[0] = w * acc[0] + bflo(ua.x);
        z[1] = w * acc[1] + bfhi(ua.x);
        z[2] = w * acc[2] + bflo(ua.y);
        z[3] = w * acc[3] + bfhi(ua.y);
        z[4] = w * acc[4] + bflo(ua.z);
        z[5] = w * acc[5] + bfhi(ua.z);
        z[6] = w * acc[6] + bflo(ua.w);
        z[7] = w * acc[7] + bfhi(ua.w);
        if (!final_it) {
            uint4 o;
            o.x = ((unsigned)f2bf(z[1] * di) << 16) | f2bf(z[0] * di);
            o.y = ((unsigned)f2bf(z[3] * di) << 16) | f2bf(z[2] * di);
            o.z = ((unsigned)f2bf(z[5] * di) << 16) | f2bf(z[4] * di);
            o.w = ((unsigned)f2bf(z[7] * di) << 16) | f2bf(z[6] * di);
            *(uint4*)&zs_out[off] = o;
        } else {
            // fused log-softmax across the 8 s==0 lanes of this node
            float m = z[0];
            #pragma unroll
            for (int j = 1; j < 8; ++j) m = fmaxf(m, z[j]);
            m = fmaxf(m, __shfl_xor(m, 1, 64));
            m = fmaxf(m, __shfl_xor(m, 2, 64));
            m = fmaxf(m, __shfl_xor(m, 4, 64));
            float se = 0.f;
            #pragma unroll
            for (int j = 0; j < 8; ++j) se += expf(z[j] - m);
            se += __shfl_xor(se, 1, 64);
            se += __shfl_xor(se, 2, 64);
            se += __shfl_xor(se, 4, 64);
            const float ls = m + logf(se);
            *(float4*)&out[off]     = make_float4(z[0] - ls, z[1] - ls, z[2] - ls, z[3] - ls);
            *(float4*)&out[off + 4] = make_float4(z[4] - ls, z[5] - ls, z[6] - ls, z[7] - ls);
        }
    }
}

// ---------------------------------------------------------------------------
extern "C" void kernel_launch(void* const* d_in, const int* in_sizes, int n_in,
                              void* d_out, int out_size, void* d_ws, size_t ws_size,
                              hipStream_t stream)
{
    const float* x  = (const float*)d_in[0];
    const int* ei   = (const int*)d_in[1];
    const float* W1 = (const float*)d_in[2];
    const float* b1 = (const float*)d_in[3];
    const float* W2 = (const float*)d_in[4];
    const float* b2 = (const float*)d_in[5];
    float* out = (float*)d_out;

    const int N = in_sizes[0] / F_IN;       // 100000
    const int E = in_sizes[1] / 2;          // 3200000
    const int* row = ei;                    // source
    const int* col = ei + E;                // target

    // workspace layout
    ushort* ah     = (ushort*)d_ws;                           // N*64 bf16 (alpha*h)
    ushort* zs_a   = ah + (long)N * C_DIM;                    // N*64 bf16
    ushort* zs_b   = zs_a + (long)N * C_DIM;                  // N*64 bf16
    float*  dinv   = (float*)(zs_b + (long)N * C_DIM);        // N
    int*    cnt    = (int*)(dinv + N);                        // N
    int*    rowptr = cnt + N;                                 // N+16 (padded)
    int*    rank   = rowptr + N + 16;                         // E
    int*    csr_src = rank + E;                               // E
    int*    sums   = csr_src + E;                             // 128
    ushort* W1p    = (ushort*)(sums + 128);                   // 131072
    ushort* W2p    = W1p + 131072;                            // 16384

    const int eblk = (E + 255) / 256;
    const int nchunks = (N + 1023) / 1024;

    // 1. weight prep + cnt zero
    prep_kernel<<<512, 256, 0, stream>>>(W1, W1p, W2, W2p, cnt, N);

    // 2. CSR build (one atomic pass)
    rank_kernel<<<eblk, 256, 0, stream>>>(col, cnt, rank, E);
    scan1_kernel<<<nchunks, 256, 0, stream>>>(cnt, rowptr, sums, dinv, N);
    scan2_kernel<<<1, 128, 0, stream>>>(sums, nchunks);
    scan3_kernel<<<(N + 256) / 256, 256, 0, stream>>>(rowptr, sums, N, E);
    fill_kernel<<<eblk, 256, 0, stream>>>(row, col, rowptr, rank, csr_src, E);

    // 3. MLP encoder (writes zs_a = bf16(h*dinv), ah = bf16(alpha*h))
    mlp_mfma_kernel<<<(N + 63) / 64, 256, 0, stream>>>(x, W1p, b1, W2p, b2,
                                                       dinv, ah, zs_a, N);

    // 4. APPNP iterations (ping-pong bf16; final fuses log-softmax -> out)
    const int gblk = (N + 3) / 4;   // one wave per node
    for (int it = 0; it < K_STEPS; ++it) {
        const ushort* in = (it & 1) ? zs_b : zs_a;
        ushort* outb     = (it & 1) ? zs_a : zs_b;
        gather8_kernel<<<gblk, 256, 0, stream>>>(rowptr, csr_src, dinv, ah,
                                                 in, outb, out, N,
                                                 it == K_STEPS - 1 ? 1 : 0);
    }
}